// Round 8
// baseline (26222.989 us; speedup 1.0000x reference)
//
#include <hip/hip_runtime.h>
#include <hip/hip_bf16.h>

#define SEQ 8192
#define HID 2048
#define NBLK 64        // persistent scan blocks (distinct CUs -> co-resident)
#define ROWS 32        // Wh rows per block (NBLK*ROWS == HID)

typedef short short8 __attribute__((ext_vector_type(8)));
typedef float floatx4 __attribute__((ext_vector_type(4)));
typedef unsigned uintx4 __attribute__((ext_vector_type(4)));

// Split 8 consecutive f32 into bf16 hi + bf16 lo fragments (RNE rounding).
__device__ __forceinline__ void split_bf16(const float* __restrict__ p,
                                           short8& hi, short8& lo) {
    const float4 f0 = *(const float4*)p;
    const float4 f1 = *(const float4*)(p + 4);
    const float f[8] = {f0.x, f0.y, f0.z, f0.w, f1.x, f1.y, f1.z, f1.w};
#pragma unroll
    for (int e = 0; e < 8; ++e) {
        const unsigned u = __float_as_uint(f[e]);
        const unsigned r = (u + 0x7fffu + ((u >> 16) & 1u)) & 0xffff0000u;
        hi[e] = (short)(r >> 16);
        const float l = f[e] - __uint_as_float(r);
        const unsigned ul = __float_as_uint(l);
        lo[e] = (short)((ul + 0x7fffu + ((ul >> 16) & 1u)) >> 16);
    }
}

// ---------------------------------------------------------------------------
// Kernel 1: xp[s,h] = sum_k x[s,k]*Wi[h,k] + bi[h]  (f32 in/out, bf16-split
// MFMA: 3 products per k-chunk, ~1e-4 abs error).
// ---------------------------------------------------------------------------
__global__ __launch_bounds__(256) void xproj_gemm(
    const float* __restrict__ x,       // [SEQ, HID]
    const float* __restrict__ Wi,      // [HID, HID]
    const float* __restrict__ bi,      // [HID]
    float* __restrict__ xp)            // [SEQ, HID]
{
    const int bn = blockIdx.x;
    const int bm = blockIdx.y;
    const int tid = threadIdx.x;
    const int wave = tid >> 6;
    const int lane = tid & 63;
    const int wM = wave & 1, wN = wave >> 1;
    const int l16 = lane & 15, kq = lane >> 4;
    const int m0 = bm * 64 + wM * 32;
    const int n0 = bn * 64 + wN * 32;

    floatx4 acc00 = {0.f,0.f,0.f,0.f}, acc01 = {0.f,0.f,0.f,0.f};
    floatx4 acc10 = {0.f,0.f,0.f,0.f}, acc11 = {0.f,0.f,0.f,0.f};

    const float* xA0 = x  + (size_t)(m0 + l16)      * HID;
    const float* xA1 = x  + (size_t)(m0 + 16 + l16) * HID;
    const float* wB0 = Wi + (size_t)(n0 + l16)      * HID;
    const float* wB1 = Wi + (size_t)(n0 + 16 + l16) * HID;

    for (int kc = 0; kc < HID; kc += 32) {
        const int k = kc + kq * 8;
        short8 a0h, a0l, a1h, a1l, b0h, b0l, b1h, b1l;
        split_bf16(xA0 + k, a0h, a0l);
        split_bf16(xA1 + k, a1h, a1l);
        split_bf16(wB0 + k, b0h, b0l);
        split_bf16(wB1 + k, b1h, b1l);
        acc00 = __builtin_amdgcn_mfma_f32_16x16x32_bf16(a0h, b0h, acc00, 0,0,0);
        acc00 = __builtin_amdgcn_mfma_f32_16x16x32_bf16(a0l, b0h, acc00, 0,0,0);
        acc00 = __builtin_amdgcn_mfma_f32_16x16x32_bf16(a0h, b0l, acc00, 0,0,0);
        acc01 = __builtin_amdgcn_mfma_f32_16x16x32_bf16(a0h, b1h, acc01, 0,0,0);
        acc01 = __builtin_amdgcn_mfma_f32_16x16x32_bf16(a0l, b1h, acc01, 0,0,0);
        acc01 = __builtin_amdgcn_mfma_f32_16x16x32_bf16(a0h, b1l, acc01, 0,0,0);
        acc10 = __builtin_amdgcn_mfma_f32_16x16x32_bf16(a1h, b0h, acc10, 0,0,0);
        acc10 = __builtin_amdgcn_mfma_f32_16x16x32_bf16(a1l, b0h, acc10, 0,0,0);
        acc10 = __builtin_amdgcn_mfma_f32_16x16x32_bf16(a1h, b0l, acc10, 0,0,0);
        acc11 = __builtin_amdgcn_mfma_f32_16x16x32_bf16(a1h, b1h, acc11, 0,0,0);
        acc11 = __builtin_amdgcn_mfma_f32_16x16x32_bf16(a1l, b1h, acc11, 0,0,0);
        acc11 = __builtin_amdgcn_mfma_f32_16x16x32_bf16(a1h, b1l, acc11, 0,0,0);
    }

    const float bi0 = bi[n0 + l16];
    const float bi1 = bi[n0 + 16 + l16];
#pragma unroll
    for (int reg = 0; reg < 4; ++reg) {
        const int mlo = m0 + kq * 4 + reg;
        const int mhi = mlo + 16;
        xp[(size_t)mlo * HID + n0 + l16]      = acc00[reg] + bi0;
        xp[(size_t)mlo * HID + n0 + 16 + l16] = acc01[reg] + bi1;
        xp[(size_t)mhi * HID + n0 + l16]      = acc10[reg] + bi0;
        xp[(size_t)mhi * HID + n0 + 16 + l16] = acc11[reg] + bi1;
    }
}

// ---------------------------------------------------------------------------
// Kernel 2: persistent recurrence, one-hop tagged exchange, BARRIER-FREE.
// Round-13 = round-12 (barrier-free chunked consumption) + LIVENESS BACKSTOP:
//  - NO s_barrier in the main loop. Each wave polls its own global slice
//    (rows [128w,+128) and [1024+128w,+128)), stages into parity h_lds[q],
//    publishes flags[q][w]=t-1 after lgkmcnt(0).
//  - Consumers process the dot in 4 column-pairs; spin on the pair's two
//    flags. NEW: the flag spin is BOUNDED (16384 LDS reads ~ 70us >> any
//    healthy wait); on timeout the lane global-polls the chunk's own rows
//    from hbuf directly (verified single-asm poll) and proceeds. Every spin
//    in the kernel is now either (a) a global poll whose exit depends only
//    on producer progress or (b) flag-spin with (a) as fallback => by
//    induction no wave can be permanently blocked => no deadlock, ever.
//    (Round-12's container death was either infra or a liveness subtlety;
//    this converts any such case into slow-but-correct, and the fast path
//    is unchanged when healthy.)
//  - hbuf 4 parities (t&3): overwrite of tag t-4 gated by the transitive
//    detect chain (all blocks stored t-2 => all waves >= t-1 => nobody
//    reads/polls <= t-3). h_lds/flags 2 parities by the same chain.
//  - Fixed pair order 0..3 keeps w[r][p] compile-time indexed (rule #20).
// Ordering: data ds_write -> s_waitcnt lgkmcnt(0) -> flag ds_write; reader:
// volatile flag spin -> asm "" memory fence -> data reads.
// ws poison 0xAAAAAAAA never equals a tag in [0, SEQ); LDS flags init -1.
// ---------------------------------------------------------------------------
__global__ __launch_bounds__(512, 1) void rnn_scan(
    const float* __restrict__ Wh,    // [HID, HID]
    const float* __restrict__ bh,    // [HID]
    const float* __restrict__ xp,    // [SEQ, HID]
    unsigned long long* hbuf,        // [4][HID] tagged exchange
    float* out)                      // [SEQ*HID + HID]
{
    __shared__ float h_lds[2][HID];      // 16 KB, parity (t-1)&1
    __shared__ unsigned flags[2][8];     // per-wave stage flags, parity

    const int b   = blockIdx.x;
    const int tid = threadIdx.x;
    const int wv  = tid >> 6;        // wave = row group (4 rows each)
    const int L   = tid & 63;
    const int row = b * ROWS + wv * 4 + L;   // meaningful when L < 4

    if (tid < 16) flags[tid >> 3][tid & 7] = 0xFFFFFFFFu;
    __syncthreads();   // once, before the loop (flag init)

    // one-time: Wh rows -> registers. Lane L covers cols 256*j+4*L+{0..3}.
    floatx4 w[4][8];
#pragma unroll
    for (int r = 0; r < 4; ++r) {
        const size_t rr = (size_t)(b * ROWS + wv * 4 + r);
#pragma unroll
        for (int j = 0; j < 8; ++j)
            w[r][j] = *(const floatx4*)(Wh + rr * HID + 256 * j + 4 * L);
    }
    const float bh_l = (L < 4) ? bh[row] : 0.f;

    float xp_cur = (L < 4) ? xp[row] : 0.f;   // step 0
    float prev_h = 0.f;

    for (int t = 0; t < SEQ; ++t) {
        float acc[4] = {0.f, 0.f, 0.f, 0.f};
        const int q = (t - 1) & 1;
        const unsigned want = (unsigned)(t - 1);

        if (t > 0) {
            const unsigned long long* src = hbuf + (size_t)((t - 1) & 3) * HID;
            const unsigned long long* s0 = src + 2 * tid;
            const unsigned long long* s1 = src + 1024 + 2 * tid;
            uintx4 p0, p1;   // [data, tag, data, tag]
            do {   // verified single-asm poll: issue+wait+consume atomic
                asm volatile(
                    "global_load_dwordx4 %0, %2, off sc0 sc1\n\t"
                    "global_load_dwordx4 %1, %3, off sc0 sc1\n\t"
                    "s_waitcnt vmcnt(0)"
                    : "=&v"(p0), "=&v"(p1)
                    : "v"(s0), "v"(s1)
                    : "memory");
            } while ((p0[1] != want) | (p0[3] != want) |
                     (p1[1] != want) | (p1[3] != want));
            // stage own slice into parity LDS buffer
            *(float2*)&h_lds[q][2 * tid] =
                make_float2(__uint_as_float(p0[0]), __uint_as_float(p0[2]));
            *(float2*)&h_lds[q][1024 + 2 * tid] =
                make_float2(__uint_as_float(p1[0]), __uint_as_float(p1[2]));
            // drain data writes, then publish this wave's flag
            asm volatile("s_waitcnt lgkmcnt(0)" ::: "memory");
            if (L == 0) flags[q][wv] = want;
            // deferred out[] store for step t-1: retires under compute
            if (L < 4) out[(size_t)(t - 1) * HID + row] = prev_h;
        }

        // prefetch next step's xp (used next iteration; fully hidden)
        float xp_next = 0.f;
        if (L < 4 && t + 1 < SEQ) xp_next = xp[(size_t)(t + 1) * HID + row];

        if (t > 0) {
            const unsigned long long* src = hbuf + (size_t)((t - 1) & 3) * HID;
            // chunked dot: 4 pairs, fixed order (compile-time w index).
            // pair p = cols [256p,256p+256) and [1024+256p,+256), staged by
            // waves 2p and 2p+1.
#pragma unroll
            for (int p = 0; p < 4; ++p) {
                volatile unsigned* vf = &flags[q][2 * p];
                int spins = 0;
                bool flagged = true;
                while ((vf[0] != want) | (vf[1] != want)) {
                    if (++spins > 16384) { flagged = false; break; }
                }
                asm volatile("" ::: "memory");   // no load hoisting past spin
                float4 hv0, hv1;
                if (flagged) {
                    hv0 = *(const float4*)&h_lds[q][256 * p + 4 * L];
                    hv1 = *(const float4*)&h_lds[q][1024 + 256 * p + 4 * L];
                } else {
                    // liveness backstop: poll this chunk's rows directly
                    // from hbuf (sound single-asm form; exits when the
                    // owning producers have stored tag t-1).
                    const unsigned long long* c0 = src + 256 * p + 4 * L;
                    const unsigned long long* c1 = src + 1024 + 256 * p + 4 * L;
                    uintx4 a0, a1, b0, b1;   // [d,tag,d,tag] x4
                    do {
                        asm volatile(
                            "global_load_dwordx4 %0, %4, off sc0 sc1\n\t"
                            "global_load_dwordx4 %1, %4, off offset:16 sc0 sc1\n\t"
                            "global_load_dwordx4 %2, %5, off sc0 sc1\n\t"
                            "global_load_dwordx4 %3, %5, off offset:16 sc0 sc1\n\t"
                            "s_waitcnt vmcnt(0)"
                            : "=&v"(a0), "=&v"(a1), "=&v"(b0), "=&v"(b1)
                            : "v"(c0), "v"(c1)
                            : "memory");
                    } while ((a0[1] != want) | (a0[3] != want) |
                             (a1[1] != want) | (a1[3] != want) |
                             (b0[1] != want) | (b0[3] != want) |
                             (b1[1] != want) | (b1[3] != want));
                    hv0 = make_float4(__uint_as_float(a0[0]),
                                      __uint_as_float(a0[2]),
                                      __uint_as_float(a1[0]),
                                      __uint_as_float(a1[2]));
                    hv1 = make_float4(__uint_as_float(b0[0]),
                                      __uint_as_float(b0[2]),
                                      __uint_as_float(b1[0]),
                                      __uint_as_float(b1[2]));
                }
#pragma unroll
                for (int r = 0; r < 4; ++r) {
                    acc[r] += w[r][p][0] * hv0.x;
                    acc[r] += w[r][p][1] * hv0.y;
                    acc[r] += w[r][p][2] * hv0.z;
                    acc[r] += w[r][p][3] * hv0.w;
                    acc[r] += w[r][p + 4][0] * hv1.x;
                    acc[r] += w[r][p + 4][1] * hv1.y;
                    acc[r] += w[r][p + 4][2] * hv1.z;
                    acc[r] += w[r][p + 4][3] * hv1.w;
                }
            }
        }

        // 64-lane butterfly reduce (proven round-0 form)
#pragma unroll
        for (int off = 32; off > 0; off >>= 1) {
#pragma unroll
            for (int r = 0; r < 4; ++r) acc[r] += __shfl_xor(acc[r], off, 64);
        }

        if (L < 4) {
            float a = acc[L] + xp_cur + bh_l;
            a = fminf(fmaxf(a, -15.f), 15.f);
            const float e = __expf(2.f * a);
            const float hval = (e - 1.f) / (e + 1.f);
            const unsigned long long tagged =
                ((unsigned long long)(unsigned)t << 32) |
                (unsigned long long)__float_as_uint(hval);
            __hip_atomic_store(&hbuf[(size_t)(t & 3) * HID + row], tagged,
                               __ATOMIC_RELAXED, __HIP_MEMORY_SCOPE_AGENT);
            prev_h = hval;
        }
        xp_cur = xp_next;
    }

    if (L < 4) {
        out[(size_t)(SEQ - 1) * HID + row] = prev_h;   // last step's output
        out[(size_t)SEQ * HID + row]       = prev_h;   // h_n
    }
}

// ---------------------------------------------------------------------------
extern "C" void kernel_launch(void* const* d_in, const int* in_sizes, int n_in,
                              void* d_out, int out_size, void* d_ws, size_t ws_size,
                              hipStream_t stream) {
    const float* x  = (const float*)d_in[0];   // [8192,2048] f32
    const float* Wi = (const float*)d_in[1];   // [2048,2048] f32
    const float* bi = (const float*)d_in[2];   // [2048] f32
    const float* Wh = (const float*)d_in[3];   // [2048,2048] f32
    const float* bh = (const float*)d_in[4];   // [2048] f32
    float* out      = (float*)d_out;           // outputs ++ h_n

    // ws: xp f32 [SEQ*HID] (64 MB) | hbuf u64 [4*HID] (64 KB)
    float* xp = (float*)d_ws;
    unsigned long long* hbuf = (unsigned long long*)(xp + (size_t)SEQ * HID);

    xproj_gemm<<<dim3(HID / 64, SEQ / 64), 256, 0, stream>>>(x, Wi, bi, xp);
    rnn_scan<<<NBLK, 512, 0, stream>>>(Wh, bh, xp, hbuf, out);
}